// Round 4
// baseline (485.253 us; speedup 1.0000x reference)
//
#include <hip/hip_runtime.h>
#include <hip/hip_bf16.h>
#include <math.h>

#define BATCH 4
#define N 2048
#define D 256
#define NH 4
#define DH 64
#define TOPK 9
#define NEG_BIG -1e30f

typedef __bf16 bf16;
typedef __bf16 bf16x8 __attribute__((ext_vector_type(8)));
typedef float f32x4 __attribute__((ext_vector_type(4)));

#define PK3(a,b,c) ((a) | ((b) << 2) | ((c) << 4))
#define PK6(a,b,c,d,e,f) ((a) | ((b) << 2) | ((c) << 4) | ((d) << 6) | ((e) << 8) | ((f) << 10))

// branch-free sorted-insert into desc top-9 (earlier index wins ties because we
// scan in ascending index order and use >= to keep incumbents above)
#define INSERT9(tv, ti, vv, jj) do {                                   \
    float ntv[TOPK]; int nti[TOPK];                                    \
    _Pragma("unroll")                                                  \
    for (int s_ = 0; s_ < TOPK; ++s_) {                                \
      float ab_ = (s_ == 0) ? 3e38f : tv[s_ - 1];                      \
      int abi_ = (s_ == 0) ? 0 : ti[s_ - 1];                           \
      if (tv[s_] >= (vv))      { ntv[s_] = tv[s_]; nti[s_] = ti[s_]; } \
      else if (ab_ >= (vv))    { ntv[s_] = (vv);   nti[s_] = (jj); }   \
      else                     { ntv[s_] = ab_;    nti[s_] = abi_; }   \
    }                                                                  \
    _Pragma("unroll")                                                  \
    for (int s_ = 0; s_ < TOPK; ++s_) { tv[s_] = ntv[s_]; ti[s_] = nti[s_]; } \
  } while (0)

__device__ __forceinline__ void async_cp16(const bf16* g, const bf16* l) {
  __builtin_amdgcn_global_load_lds(
      (const __attribute__((address_space(1))) void*)(uintptr_t)g,
      (__attribute__((address_space(3))) void*)(uintptr_t)l, 16, 0, 0);
}

// ---------------------------------------------------------------------------
// prep: blk<8192: x -> XsN (L2-norm, 3-way split, stride 768)
//       blk<16384: x -> XsRaw (2-way split, stride 512)
//       else: Wq/Wk/Wv/Wo -> Wt (transpose + 2-way split)
// ---------------------------------------------------------------------------
__global__ __launch_bounds__(64) void prep_kernel(const float* __restrict__ x,
                                                  const float* __restrict__ Wq,
                                                  const float* __restrict__ Wk,
                                                  const float* __restrict__ Wv,
                                                  const float* __restrict__ Wo,
                                                  bf16* __restrict__ XsN,
                                                  bf16* __restrict__ XsRaw,
                                                  bf16* __restrict__ Wt) {
  int blk = blockIdx.x;
  int lane = threadIdx.x;
  if (blk < 16384) {
    int row = blk & 8191;
    bool norm = blk < 8192;
    float4 v = *(const float4*)(x + (size_t)row * D + lane * 4);
    float sc = 1.0f;
    if (norm) {
      float ss = v.x * v.x + v.y * v.y + v.z * v.z + v.w * v.w;
      for (int off = 32; off; off >>= 1) ss += __shfl_down(ss, off);
      ss = __shfl(ss, 0);
      sc = 1.0f / fmaxf(sqrtf(ss), 1e-12f);
    }
    float xs[4] = {v.x * sc, v.y * sc, v.z * sc, v.w * sc};
    bf16* o = (norm ? XsN + (size_t)row * 768 : XsRaw + (size_t)row * 512) + lane * 4;
#pragma unroll
    for (int j = 0; j < 4; ++j) {
      float xv = xs[j];
      bf16 h = (bf16)xv;
      float r1 = xv - (float)h;
      bf16 m = (bf16)r1;
      o[j] = h;
      o[256 + j] = m;
      if (norm) o[512 + j] = (bf16)(r1 - (float)m);
    }
  } else {
    int jj = blk - 16384;
    const float* W = (jj < 256) ? Wq : (jj < 512) ? Wk : (jj < 768) ? Wv : Wo;
    int j = jj & 255;
    bf16* dst = Wt + (size_t)jj * 512;
    for (int k = lane; k < 256; k += 64) {
      float w = W[(size_t)k * D + j];
      bf16 h = (bf16)w;
      dst[k] = h;
      dst[256 + k] = (bf16)(w - (float)h);
    }
  }
}

// ---------------------------------------------------------------------------
// MFMA GEMM, m97-style staging (global_load_lds 16B, XOR-swizzled source).
// mode 0: write C[i][j] to global (ldc).
// mode 1 (sim): symmetric A@A^T; NO C materialization — per-row top-9 of the
//   128x128 tile (both directions for off-diag blocks) -> cand[b][row][slot][9].
// ---------------------------------------------------------------------------
__global__ __launch_bounds__(256) void gemm_bt_kernel(const bf16* __restrict__ A,
                                                      const bf16* __restrict__ B,
                                                      float* __restrict__ C,
                                                      float2* __restrict__ cand,
                                                      int lda, int ldb, int ldc,
                                                      int nsteps, int amap, int bmap,
                                                      long sA, long sB,
                                                      int mode) {
  if (mode && blockIdx.x < blockIdx.y) return;
  __shared__ __align__(16) char smem[51712];
  bf16* As = (bf16*)smem;            // [128*64] = 16 KB
  bf16* Bs = (bf16*)(smem + 16384);  // [128*64] = 16 KB
  int tid = threadIdx.x;
  int lane = tid & 63;
  int wv = tid >> 6;
  int wm = (wv >> 1) * 64;
  int wn = (wv & 1) * 64;
  int row0 = blockIdx.y * 128;
  int col0 = blockIdx.x * 128;
  int z = blockIdx.z;
  const bf16* Ab = A + (size_t)z * sA + (size_t)row0 * lda;
  const bf16* Bb = B + (size_t)z * sB + (size_t)col0 * ldb;

  int rbase = tid >> 3;
  int gperm = (tid & 7) ^ (rbase & 7);
  const bf16* ga0 = Ab + (size_t)rbase * lda + gperm * 8;
  const bf16* gb0 = Bb + (size_t)rbase * ldb + gperm * 8;
  const bf16* la0 = As + (size_t)tid * 8;
  const bf16* lb0 = Bs + (size_t)tid * 8;

  int fr = lane & 15;
  int fq = (lane >> 4) * 8;

  f32x4 acc[4][4] = {};

  for (int st = 0; st < nsteps; ++st) {
    int ch = st >> 2;
    int aoff = (((amap >> (ch * 2)) & 3) << 8) | ((st & 3) << 6);
    int boff = (((bmap >> (ch * 2)) & 3) << 8) | ((st & 3) << 6);
#pragma unroll
    for (int q = 0; q < 4; ++q)
      async_cp16(ga0 + (size_t)q * 32 * lda + aoff, la0 + q * 2048);
#pragma unroll
    for (int q = 0; q < 4; ++q)
      async_cp16(gb0 + (size_t)q * 32 * ldb + boff, lb0 + q * 2048);
    __syncthreads();
#pragma unroll
    for (int ks = 0; ks < 64; ks += 32) {
      bf16x8 af[4], bfr[4];
#pragma unroll
      for (int mi = 0; mi < 4; ++mi) {
        int r = wm + mi * 16 + fr;
        int G = (ks + fq) >> 3;
        af[mi] = *(const bf16x8*)&As[r * 64 + ((G ^ (r & 7)) << 3)];
      }
#pragma unroll
      for (int nj = 0; nj < 4; ++nj) {
        int r = wn + nj * 16 + fr;
        int G = (ks + fq) >> 3;
        bfr[nj] = *(const bf16x8*)&Bs[r * 64 + ((G ^ (r & 7)) << 3)];
      }
#pragma unroll
      for (int mi = 0; mi < 4; ++mi)
#pragma unroll
        for (int nj = 0; nj < 4; ++nj)
          acc[mi][nj] = __builtin_amdgcn_mfma_f32_16x16x32_bf16(af[mi], bfr[nj], acc[mi][nj], 0, 0, 0);
    }
    __syncthreads();
  }

  int er = (lane >> 4) * 4;
  int ec = lane & 15;

  if (mode == 0) {
    float* Cb = C;
#pragma unroll
    for (int mi = 0; mi < 4; ++mi)
#pragma unroll
      for (int nj = 0; nj < 4; ++nj) {
        int rb = row0 + wm + mi * 16 + er;
        int cb = col0 + wn + nj * 16 + ec;
#pragma unroll
        for (int reg = 0; reg < 4; ++reg)
          Cb[(size_t)(rb + reg) * ldc + cb] = acc[mi][nj][reg];
      }
    return;
  }

  // ---- mode 1: fused per-tile top-9 epilogue ----
  float* Cs = (float*)smem;                   // [128][65] fp32 = 33280 B
  float2* scr = (float2*)(smem + 33280);      // 256*9*8 = 18432 B
  bool do_mirror = (blockIdx.x != blockIdx.y);
  float dv[TOPK]; int di[TOPK];
#pragma unroll
  for (int s = 0; s < TOPK; ++s) { dv[s] = NEG_BIG; di[s] = 0x7fffffff; }

  for (int half = 0; half < 2; ++half) {
    __syncthreads();  // smem free (K-loop or previous half done)
    if ((wv & 1) == half) {
#pragma unroll
      for (int mi = 0; mi < 4; ++mi)
#pragma unroll
        for (int nj = 0; nj < 4; ++nj)
#pragma unroll
          for (int reg = 0; reg < 4; ++reg)
            Cs[(wm + mi * 16 + er + reg) * 65 + nj * 16 + ec] = acc[mi][nj][reg];
    }
    __syncthreads();
    // direction 0: per tile-row top-9 (accumulated across halves in regs)
    {
      int r = tid >> 1;
      int j0 = (tid & 1) * 32;
      int gbase = col0 + half * 64 + j0;
      for (int j = 0; j < 32; ++j) {
        float vv = Cs[r * 65 + j0 + j];
        if (vv > dv[TOPK - 1]) INSERT9(dv, di, vv, gbase + j);
      }
    }
    // direction 1: per tile-col top-9 (mirror rows), complete within this half
    if (do_mirror) {
      int c = tid >> 2;
      int i0 = (tid & 3) * 32;
      float ev[TOPK]; int ei[TOPK];
#pragma unroll
      for (int s = 0; s < TOPK; ++s) { ev[s] = NEG_BIG; ei[s] = 0x7fffffff; }
      for (int i = 0; i < 32; ++i) {
        float vv = Cs[(i0 + i) * 65 + c];
        if (vv > ev[TOPK - 1]) INSERT9(ev, ei, vv, row0 + i0 + i);
      }
#pragma unroll
      for (int s = 0; s < TOPK; ++s)
        scr[tid * TOPK + s] = make_float2(ev[s], __int_as_float(ei[s]));
      __syncthreads();
      if ((tid & 3) == 0) {
        int mrow = col0 + half * 64 + c;
        float2* dst = &cand[(((size_t)z * N + mrow) * 16 + blockIdx.y) * TOPK];
        for (int rs = 0; rs < TOPK; ++rs) {
          float bv = NEG_BIG; int bi = 0x7fffffff; int bs = 0;
          for (int e = 0; e < 4 * TOPK; ++e) {
            float2 cd = scr[tid * TOPK + e];
            float vv = cd.x; int ii = __float_as_int(cd.y);
            if (vv > bv || (vv == bv && ii < bi)) { bv = vv; bi = ii; bs = e; }
          }
          dst[rs] = make_float2(bv, __int_as_float(bi));
          scr[tid * TOPK + bs].x = -3e38f;
        }
      }
      __syncthreads();
    }
  }
  // finalize direction 0
  __syncthreads();
#pragma unroll
  for (int s = 0; s < TOPK; ++s)
    scr[tid * TOPK + s] = make_float2(dv[s], __int_as_float(di[s]));
  __syncthreads();
  if ((tid & 1) == 0) {
    int r = tid >> 1;
    float2* dst = &cand[(((size_t)z * N + row0 + r) * 16 + blockIdx.x) * TOPK];
    for (int rs = 0; rs < TOPK; ++rs) {
      float bv = NEG_BIG; int bi = 0x7fffffff; int bs = 0;
      for (int e = 0; e < 2 * TOPK; ++e) {
        float2 cd = scr[tid * TOPK + e];
        float vv = cd.x; int ii = __float_as_int(cd.y);
        if (vv > bv || (vv == bv && ii < bi)) { bv = vv; bi = ii; bs = e; }
      }
      dst[rs] = make_float2(bv, __int_as_float(bi));
      scr[tid * TOPK + bs].x = -3e38f;
    }
  }
}

// ---------------------------------------------------------------------------
// merge 16 candidate lists per row -> exact global top-9 -> adjacency bits.
// One wave per row; mask pre-zeroed.
// ---------------------------------------------------------------------------
__global__ __launch_bounds__(256) void knn_merge_kernel(const float2* __restrict__ cand,
                                                        unsigned* __restrict__ mask) {
  int row = blockIdx.x * 4 + (threadIdx.x >> 6);
  int lane = threadIdx.x & 63;
  int b = row >> 11, r = row & 2047;
  const float2* src = cand + (size_t)row * (16 * TOPK);
  float v[3]; int idx[3];
#pragma unroll
  for (int q = 0; q < 3; ++q) {
    int e = q * 64 + lane;
    if (e < 16 * TOPK) {
      float2 cd = src[e];
      v[q] = cd.x; idx[q] = __float_as_int(cd.y);
    } else { v[q] = -3e38f; idx[q] = 0x7fffffff; }
  }
  for (int rs = 0; rs < TOPK; ++rs) {
    float bv = v[0]; int bi = idx[0]; int bq = 0;
#pragma unroll
    for (int q = 1; q < 3; ++q)
      if (v[q] > bv || (v[q] == bv && idx[q] < bi)) { bv = v[q]; bi = idx[q]; bq = q; }
    int bc = bq * 64 + lane;
    for (int off = 32; off; off >>= 1) {
      float ov = __shfl_down(bv, off);
      int oi = __shfl_down(bi, off);
      int oc = __shfl_down(bc, off);
      if (ov > bv || (ov == bv && oi < bi)) { bv = ov; bi = oi; bc = oc; }
    }
    bi = __shfl(bi, 0);
    bc = __shfl(bc, 0);
    if (lane == (bc & 63)) v[bc >> 6] = -3e38f;
    if (lane == 0) {
      atomicOr(&mask[(((size_t)b << 11) + r) * 64 + (bi >> 5)], 1u << (bi & 31));
      atomicOr(&mask[(((size_t)b << 11) + bi) * 64 + (r >> 5)], 1u << (r & 31));
    }
  }
}

// ---------------------------------------------------------------------------
// sparse attention: 4 waves/block, one (b,n) row per wave; writes bf16-split
// aos directly (fuses the old ao->aos splitrows pass).
// ---------------------------------------------------------------------------
__global__ __launch_bounds__(256) void attn_kernel(const float* __restrict__ qkv,
                                                   const unsigned* __restrict__ mask,
                                                   bf16* __restrict__ aos) {
  __shared__ float sq[4][256];
  __shared__ unsigned short nbr[4][2048];
  __shared__ int s_nn[4];
  int wv = threadIdx.x >> 6;
  int lane = threadIdx.x & 63;
  int bn = blockIdx.x * 4 + wv;
  int b = bn >> 11;
  if (lane == 0) s_nn[wv] = 0;
  *(float4*)&sq[wv][lane * 4] = *(const float4*)(qkv + (size_t)bn * 768 + lane * 4);
  __syncthreads();
  unsigned bits = mask[(size_t)bn * (N / 32) + lane];
  while (bits) {
    int bit = __ffs(bits) - 1;
    bits &= bits - 1;
    int p = atomicAdd(&s_nn[wv], 1);
    nbr[wv][p] = (unsigned short)(lane * 32 + bit);
  }
  __syncthreads();
  int nn = s_nn[wv];
  const float* base = qkv + (size_t)b * N * 768;
  float acc[4] = {0.f, 0.f, 0.f, 0.f};

  auto score4 = [&](int j, float* s) {
    const float* kr = base + (size_t)j * 768 + 256;
#pragma unroll
    for (int h = 0; h < 4; ++h) {
      float a = 0.f;
#pragma unroll
      for (int c = 0; c < DH; c += 4) {
        float4 kk = *(const float4*)(kr + h * DH + c);
        a += sq[wv][h * DH + c] * kk.x + sq[wv][h * DH + c + 1] * kk.y +
             sq[wv][h * DH + c + 2] * kk.z + sq[wv][h * DH + c + 3] * kk.w;
      }
      s[h] = a * 0.125f;
    }
  };

  if (nn <= 64) {
    float s[4] = {NEG_BIG, NEG_BIG, NEG_BIG, NEG_BIG};
    if (lane < nn) score4(nbr[wv][lane], s);
    float w[4], l[4];
#pragma unroll
    for (int h = 0; h < 4; ++h) {
      float m = s[h];
      for (int off = 32; off; off >>= 1) m = fmaxf(m, __shfl_down(m, off));
      m = __shfl(m, 0);
      float e = (lane < nn) ? __expf(s[h] - m) : 0.f;
      float ls = e;
      for (int off = 32; off; off >>= 1) ls += __shfl_down(ls, off);
      l[h] = __shfl(ls, 0);
      w[h] = e;
    }
    int i = 0;
    for (; i + 4 <= nn; i += 4) {
      int j0 = nbr[wv][i + 0], j1 = nbr[wv][i + 1];
      int j2 = nbr[wv][i + 2], j3 = nbr[wv][i + 3];
      const float* p0 = base + (size_t)j0 * 768 + 512;
      const float* p1 = base + (size_t)j1 * 768 + 512;
      const float* p2 = base + (size_t)j2 * 768 + 512;
      const float* p3 = base + (size_t)j3 * 768 + 512;
#pragma unroll
      for (int h = 0; h < 4; ++h) {
        acc[h] += __shfl(w[h], i + 0) * p0[h * DH + lane] +
                  __shfl(w[h], i + 1) * p1[h * DH + lane] +
                  __shfl(w[h], i + 2) * p2[h * DH + lane] +
                  __shfl(w[h], i + 3) * p3[h * DH + lane];
      }
    }
    for (; i < nn; ++i) {
      const float* p0 = base + (size_t)nbr[wv][i] * 768 + 512;
#pragma unroll
      for (int h = 0; h < 4; ++h) acc[h] += __shfl(w[h], i) * p0[h * DH + lane];
    }
#pragma unroll
    for (int h = 0; h < 4; ++h) acc[h] /= l[h];
  } else {
    float m[4] = {NEG_BIG, NEG_BIG, NEG_BIG, NEG_BIG};
    for (int i0 = 0; i0 < nn; i0 += 64) {
      float s[4] = {NEG_BIG, NEG_BIG, NEG_BIG, NEG_BIG};
      if (i0 + lane < nn) score4(nbr[wv][i0 + lane], s);
#pragma unroll
      for (int h = 0; h < 4; ++h) m[h] = fmaxf(m[h], s[h]);
    }
#pragma unroll
    for (int h = 0; h < 4; ++h) {
      for (int off = 32; off; off >>= 1) m[h] = fmaxf(m[h], __shfl_down(m[h], off));
      m[h] = __shfl(m[h], 0);
    }
    float l[4] = {0.f, 0.f, 0.f, 0.f};
    for (int i0 = 0; i0 < nn; i0 += 64) {
      float s[4] = {NEG_BIG, NEG_BIG, NEG_BIG, NEG_BIG};
      if (i0 + lane < nn) score4(nbr[wv][i0 + lane], s);
      float e[4];
#pragma unroll
      for (int h = 0; h < 4; ++h) {
        e[h] = (i0 + lane < nn) ? __expf(s[h] - m[h]) : 0.f;
        float ls = e[h];
        for (int off = 32; off; off >>= 1) ls += __shfl_down(ls, off);
        l[h] += __shfl(ls, 0);
      }
      int lim = min(64, nn - i0);
      for (int ii = 0; ii < lim; ++ii) {
        const float* p0 = base + (size_t)nbr[wv][i0 + ii] * 768 + 512;
#pragma unroll
        for (int h = 0; h < 4; ++h) acc[h] += __shfl(e[h], ii) * p0[h * DH + lane];
      }
    }
#pragma unroll
    for (int h = 0; h < 4; ++h) acc[h] /= l[h];
  }
#pragma unroll
  for (int h = 0; h < 4; ++h) {
    float a = acc[h];
    bf16 hi = (bf16)a;
    aos[(size_t)bn * 512 + h * DH + lane] = hi;
    aos[(size_t)bn * 512 + 256 + h * DH + lane] = (bf16)(a - (float)hi);
  }
}

// ---------------------------------------------------------------------------
// epilogue: u = x + proj + bo; out = LN(u)*gamma + beta
// ---------------------------------------------------------------------------
__global__ __launch_bounds__(64) void ln_kernel(const float* __restrict__ x,
                                                const float* __restrict__ proj,
                                                const float* __restrict__ bo,
                                                const float* __restrict__ gamma,
                                                const float* __restrict__ beta,
                                                float* __restrict__ out) {
  int row = blockIdx.x;
  int lane = threadIdx.x;
  size_t base = (size_t)row * D + lane * 4;
  float4 xv = *(const float4*)(x + base);
  float4 pv = *(const float4*)(proj + base);
  float4 bv = *(const float4*)(bo + lane * 4);
  float u0 = xv.x + pv.x + bv.x, u1 = xv.y + pv.y + bv.y;
  float u2 = xv.z + pv.z + bv.z, u3 = xv.w + pv.w + bv.w;
  float s = u0 + u1 + u2 + u3;
  for (int off = 32; off; off >>= 1) s += __shfl_down(s, off);
  s = __shfl(s, 0);
  float mean = s * (1.0f / D);
  float d0 = u0 - mean, d1 = u1 - mean, d2 = u2 - mean, d3 = u3 - mean;
  float ss = d0 * d0 + d1 * d1 + d2 * d2 + d3 * d3;
  for (int off = 32; off; off >>= 1) ss += __shfl_down(ss, off);
  ss = __shfl(ss, 0);
  float rstd = rsqrtf(ss * (1.0f / D) + 1e-5f);
  float4 gv = *(const float4*)(gamma + lane * 4);
  float4 be = *(const float4*)(beta + lane * 4);
  float4 o;
  o.x = d0 * rstd * gv.x + be.x;
  o.y = d1 * rstd * gv.y + be.y;
  o.z = d2 * rstd * gv.z + be.z;
  o.w = d3 * rstd * gv.w + be.w;
  *(float4*)(out + base) = o;
}

// ---------------------------------------------------------------------------
// Workspace (75.5 MB flat, no aliasing; harness proven >= 83.1 MB by round 3
// taking the big path):
//   XsN   [0,        12582912)
//   cand  [12582912, 22020096)   4*2048*16*9 float2
//   mask  [22020096, 24117248)
//   Wt    [24117248, 25165824)
//   XsRaw [25165824, 33554432)
//   qkv   [33554432, 58720256)
//   aos   [58720256, 67108864)
//   proj  [67108864, 75497472)
// ---------------------------------------------------------------------------
extern "C" void kernel_launch(void* const* d_in, const int* in_sizes, int n_in,
                              void* d_out, int out_size, void* d_ws, size_t ws_size,
                              hipStream_t stream) {
  const float* x     = (const float*)d_in[0];
  const float* Wq    = (const float*)d_in[1];
  const float* Wk    = (const float*)d_in[2];
  const float* Wv    = (const float*)d_in[3];
  const float* Wo    = (const float*)d_in[4];
  const float* bo    = (const float*)d_in[5];
  const float* gamma = (const float*)d_in[6];
  const float* beta  = (const float*)d_in[7];
  float* out = (float*)d_out;

  char* ws = (char*)d_ws;
  bf16* XsN      = (bf16*)(ws);
  float2* cand   = (float2*)(ws + 12582912);
  unsigned* mask = (unsigned*)(ws + 22020096);
  bf16* Wt       = (bf16*)(ws + 24117248);
  bf16* XsRaw    = (bf16*)(ws + 25165824);
  float* qkv     = (float*)(ws + 33554432);
  bf16* aos      = (bf16*)(ws + 58720256);
  float* proj    = (float*)(ws + 67108864);

  const int AMAP_SIM = PK6(0, 1, 0, 1, 0, 2);
  const int BMAP_SIM = PK6(0, 0, 1, 1, 2, 0);
  const int AMAP_2T  = PK3(0, 1, 0);
  const int BMAP_2T  = PK3(0, 0, 1);

  (void)hipMemsetAsync(mask, 0, (size_t)BATCH * N * (N / 32) * sizeof(unsigned), stream);
  prep_kernel<<<17408, 64, 0, stream>>>(x, Wq, Wk, Wv, Wo, XsN, XsRaw, Wt);

  gemm_bt_kernel<<<dim3(16, 16, 4), 256, 0, stream>>>(
      XsN, XsN, nullptr, cand, 768, 768, 0, 24, AMAP_SIM, BMAP_SIM,
      (long)N * 768, (long)N * 768, 1);
  knn_merge_kernel<<<(BATCH * N) / 4, 256, 0, stream>>>(cand, mask);

  gemm_bt_kernel<<<dim3(6, 64, 1), 256, 0, stream>>>(
      XsRaw, Wt, qkv, nullptr, 512, 512, 768, 12, AMAP_2T, BMAP_2T, 0, 0, 0);

  attn_kernel<<<(BATCH * N) / 4, 256, 0, stream>>>(qkv, mask, aos);

  gemm_bt_kernel<<<dim3(2, 64, 1), 256, 0, stream>>>(
      aos, Wt + (size_t)768 * 512, proj, nullptr, 512, 512, D, 12, AMAP_2T, BMAP_2T, 0, 0, 0);
  ln_kernel<<<BATCH * N, 64, 0, stream>>>(x, proj, bo, gamma, beta, out);
}

// Round 6
// 283.551 us; speedup vs baseline: 1.7113x; 1.7113x over previous
//
#include <hip/hip_runtime.h>
#include <hip/hip_bf16.h>
#include <math.h>

#define BATCH 4
#define N 2048
#define D 256
#define NH 4
#define DH 64
#define TOPK 9
#define NEG_BIG -1e30f

typedef __bf16 bf16;
typedef __bf16 bf16x8 __attribute__((ext_vector_type(8)));
typedef float f32x4 __attribute__((ext_vector_type(4)));

#define PK3(a,b,c) ((a) | ((b) << 2) | ((c) << 4))
#define PK6(a,b,c,d,e,f) ((a) | ((b) << 2) | ((c) << 4) | ((d) << 6) | ((e) << 8) | ((f) << 10))

// branch-free sorted-insert into desc top-9; ascending-index scan + ">=" keeps
// earlier index on ties (matches lax.top_k set semantics)
#define INSERT9(tv, ti, vv, jj) do {                                   \
    float ntv[TOPK]; int nti[TOPK];                                    \
    _Pragma("unroll")                                                  \
    for (int s_ = 0; s_ < TOPK; ++s_) {                                \
      float ab_ = (s_ == 0) ? 3e38f : tv[s_ - 1];                      \
      int abi_ = (s_ == 0) ? 0 : ti[s_ - 1];                           \
      if (tv[s_] >= (vv))      { ntv[s_] = tv[s_]; nti[s_] = ti[s_]; } \
      else if (ab_ >= (vv))    { ntv[s_] = (vv);   nti[s_] = (jj); }   \
      else                     { ntv[s_] = ab_;    nti[s_] = abi_; }   \
    }                                                                  \
    _Pragma("unroll")                                                  \
    for (int s_ = 0; s_ < TOPK; ++s_) { tv[s_] = ntv[s_]; ti[s_] = nti[s_]; } \
  } while (0)

__device__ __forceinline__ void async_cp16(const bf16* g, const bf16* l) {
  __builtin_amdgcn_global_load_lds(
      (const __attribute__((address_space(1))) void*)(uintptr_t)g,
      (__attribute__((address_space(3))) void*)(uintptr_t)l, 16, 0, 0);
}

// ---------------------------------------------------------------------------
// prep phase 1: blk<8192: x -> XsN (L2-norm, 3-way split, stride 768)
//               blk>=8192: W{q,k,v,o} -> Wt (transpose + 2-way split)
// ---------------------------------------------------------------------------
__global__ __launch_bounds__(64) void prep_xn_w_kernel(const float* __restrict__ x,
                                                       const float* __restrict__ Wq,
                                                       const float* __restrict__ Wk,
                                                       const float* __restrict__ Wv,
                                                       const float* __restrict__ Wo,
                                                       bf16* __restrict__ XsN,
                                                       bf16* __restrict__ Wt) {
  int blk = blockIdx.x;
  int lane = threadIdx.x;
  if (blk < 8192) {
    float4 v = *(const float4*)(x + (size_t)blk * D + lane * 4);
    float ss = v.x * v.x + v.y * v.y + v.z * v.z + v.w * v.w;
    for (int off = 32; off; off >>= 1) ss += __shfl_down(ss, off);
    ss = __shfl(ss, 0);
    float sc = 1.0f / fmaxf(sqrtf(ss), 1e-12f);
    float xs[4] = {v.x * sc, v.y * sc, v.z * sc, v.w * sc};
    bf16* o = XsN + (size_t)blk * 768 + lane * 4;
#pragma unroll
    for (int j = 0; j < 4; ++j) {
      float xv = xs[j];
      bf16 h = (bf16)xv;
      float r1 = xv - (float)h;
      bf16 m = (bf16)r1;
      o[j] = h;
      o[256 + j] = m;
      o[512 + j] = (bf16)(r1 - (float)m);
    }
  } else {
    int jj = blk - 8192;
    const float* W = (jj < 256) ? Wq : (jj < 512) ? Wk : (jj < 768) ? Wv : Wo;
    int j = jj & 255;
    bf16* dst = Wt + (size_t)jj * 512;
    for (int k = lane; k < 256; k += 64) {
      float w = W[(size_t)k * D + j];
      bf16 h = (bf16)w;
      dst[k] = h;
      dst[256 + k] = (bf16)(w - (float)h);
    }
  }
}

// prep phase 2: x -> XsRaw (2-way split, stride 512) — runs after sim is dead
__global__ __launch_bounds__(64) void prep_raw_kernel(const float* __restrict__ x,
                                                      bf16* __restrict__ XsRaw) {
  int row = blockIdx.x;
  int lane = threadIdx.x;
  float4 v = *(const float4*)(x + (size_t)row * D + lane * 4);
  float xs[4] = {v.x, v.y, v.z, v.w};
  bf16* o = XsRaw + (size_t)row * 512 + lane * 4;
#pragma unroll
  for (int j = 0; j < 4; ++j) {
    bf16 h = (bf16)xs[j];
    o[j] = h;
    o[256 + j] = (bf16)(xs[j] - (float)h);
  }
}

// ---------------------------------------------------------------------------
// MFMA GEMM, m97-style staging (global_load_lds 16B, XOR-swizzled source).
// mode 0: generic C = A@B^T, grid (Nc/128, M/128).
// mode 1: symmetric sim = A@A^T; compact triangular grid (136 pairs, z=batch),
//         mirror-write the transpose for off-diagonal tiles.
// ---------------------------------------------------------------------------
__global__ __launch_bounds__(256) void gemm_bt_kernel(const bf16* __restrict__ A,
                                                      const bf16* __restrict__ B,
                                                      float* __restrict__ C,
                                                      int lda, int ldb, int ldc,
                                                      int nsteps, int amap, int bmap,
                                                      long sA, long sB, long sC,
                                                      int mode) {
  __shared__ bf16 As[128 * 64];
  __shared__ bf16 Bs[128 * 64];
  int tid = threadIdx.x;
  int lane = tid & 63;
  int wv = tid >> 6;
  int wm = (wv >> 1) * 64;
  int wn = (wv & 1) * 64;
  int bx, by;
  if (mode) {  // triangular decode: enumerate (by, bx>=by) row by row
    int t = blockIdx.x;
    by = 0;
    while (t >= 16 - by) { t -= 16 - by; ++by; }
    bx = by + t;
  } else {
    bx = blockIdx.x;
    by = blockIdx.y;
  }
  int row0 = by * 128;
  int col0 = bx * 128;
  int z = blockIdx.z;
  const bf16* Ab = A + (size_t)z * sA + (size_t)row0 * lda;
  const bf16* Bb = B + (size_t)z * sB + (size_t)col0 * ldb;
  float* Cb = C + (size_t)z * sC;

  int rbase = tid >> 3;
  int gperm = (tid & 7) ^ (rbase & 7);
  const bf16* ga0 = Ab + (size_t)rbase * lda + gperm * 8;
  const bf16* gb0 = Bb + (size_t)rbase * ldb + gperm * 8;
  const bf16* la0 = As + (size_t)tid * 8;
  const bf16* lb0 = Bs + (size_t)tid * 8;

  int fr = lane & 15;
  int fq = (lane >> 4) * 8;

  f32x4 acc[4][4] = {};

  for (int st = 0; st < nsteps; ++st) {
    int ch = st >> 2;
    int aoff = (((amap >> (ch * 2)) & 3) << 8) | ((st & 3) << 6);
    int boff = (((bmap >> (ch * 2)) & 3) << 8) | ((st & 3) << 6);
#pragma unroll
    for (int q = 0; q < 4; ++q)
      async_cp16(ga0 + (size_t)q * 32 * lda + aoff, la0 + q * 2048);
#pragma unroll
    for (int q = 0; q < 4; ++q)
      async_cp16(gb0 + (size_t)q * 32 * ldb + boff, lb0 + q * 2048);
    __syncthreads();
#pragma unroll
    for (int ks = 0; ks < 64; ks += 32) {
      bf16x8 af[4], bfr[4];
#pragma unroll
      for (int mi = 0; mi < 4; ++mi) {
        int r = wm + mi * 16 + fr;
        int G = (ks + fq) >> 3;
        af[mi] = *(const bf16x8*)&As[r * 64 + ((G ^ (r & 7)) << 3)];
      }
#pragma unroll
      for (int nj = 0; nj < 4; ++nj) {
        int r = wn + nj * 16 + fr;
        int G = (ks + fq) >> 3;
        bfr[nj] = *(const bf16x8*)&Bs[r * 64 + ((G ^ (r & 7)) << 3)];
      }
#pragma unroll
      for (int mi = 0; mi < 4; ++mi)
#pragma unroll
        for (int nj = 0; nj < 4; ++nj)
          acc[mi][nj] = __builtin_amdgcn_mfma_f32_16x16x32_bf16(af[mi], bfr[nj], acc[mi][nj], 0, 0, 0);
    }
    __syncthreads();
  }

  int er = (lane >> 4) * 4;
  int ec = lane & 15;
#pragma unroll
  for (int mi = 0; mi < 4; ++mi)
#pragma unroll
    for (int nj = 0; nj < 4; ++nj) {
      int rb = row0 + wm + mi * 16 + er;
      int cb = col0 + wn + nj * 16 + ec;
#pragma unroll
      for (int reg = 0; reg < 4; ++reg)
        Cb[(size_t)(rb + reg) * ldc + cb] = acc[mi][nj][reg];
      if (mode && bx != by) {
#pragma unroll
        for (int reg = 0; reg < 4; ++reg)
          Cb[(size_t)cb * ldc + rb + reg] = acc[mi][nj][reg];
      }
    }
}

// ---------------------------------------------------------------------------
// top-9 per row of sim (one wave per row), float4-vectorized scan
// ---------------------------------------------------------------------------
__global__ __launch_bounds__(64) void topk_kernel(const float* __restrict__ sim,
                                                  int* __restrict__ out) {
  int row = blockIdx.x;
  int lane = threadIdx.x;
  const float* srow = sim + (size_t)row * N;
  float tv[TOPK];
  int ti[TOPK];
#pragma unroll
  for (int s = 0; s < TOPK; ++s) { tv[s] = NEG_BIG; ti[s] = 0x7fffffff; }
  for (int it = 0; it < N / 256; ++it) {
    int j4 = it * 256 + lane * 4;
    float4 v = *(const float4*)(srow + j4);
    if (v.x > tv[TOPK - 1]) INSERT9(tv, ti, v.x, j4 + 0);
    if (v.y > tv[TOPK - 1]) INSERT9(tv, ti, v.y, j4 + 1);
    if (v.z > tv[TOPK - 1]) INSERT9(tv, ti, v.z, j4 + 2);
    if (v.w > tv[TOPK - 1]) INSERT9(tv, ti, v.w, j4 + 3);
  }
  __shared__ float sv[64 * TOPK];
  __shared__ int si[64 * TOPK];
#pragma unroll
  for (int s = 0; s < TOPK; ++s) { sv[lane * TOPK + s] = tv[s]; si[lane * TOPK + s] = ti[s]; }
  __syncthreads();
  for (int r = 0; r < TOPK; ++r) {
    float bv = NEG_BIG;
    int bj = 0x7fffffff;
    int bslot = lane * TOPK;
#pragma unroll
    for (int s = 0; s < TOPK; ++s) {
      float vv = sv[lane * TOPK + s];
      int jj = si[lane * TOPK + s];
      if (vv > bv || (vv == bv && jj < bj)) { bv = vv; bj = jj; bslot = lane * TOPK + s; }
    }
    for (int off = 32; off; off >>= 1) {
      float ov = __shfl_down(bv, off);
      int oj = __shfl_down(bj, off);
      int os = __shfl_down(bslot, off);
      if (ov > bv || (ov == bv && oj < bj)) { bv = ov; bj = oj; bslot = os; }
    }
    bj = __shfl(bj, 0);
    bslot = __shfl(bslot, 0);
    if (lane == 0) {
      out[(size_t)row * TOPK + r] = bj;
      sv[bslot] = -1e38f;
    }
    __syncthreads();
  }
}

// ---------------------------------------------------------------------------
// adjacency bitmask (mask pre-zeroed)
// ---------------------------------------------------------------------------
__global__ void adj_kernel(const int* __restrict__ topk, unsigned* __restrict__ mask) {
  int t = blockIdx.x * blockDim.x + threadIdx.x;
  if (t >= BATCH * N * TOPK) return;
  int bn = t / TOPK;
  int b = bn / N, n = bn % N;
  int m = topk[t];
  atomicOr(&mask[((size_t)b * N + n) * (N / 32) + (m >> 5)], 1u << (m & 31));
  atomicOr(&mask[((size_t)b * N + m) * (N / 32) + (n >> 5)], 1u << (n & 31));
}

// ---------------------------------------------------------------------------
// sparse attention: 4 waves/block, one (b,n) row per wave; writes bf16-split
// aos (stride 512) directly.
// ---------------------------------------------------------------------------
__global__ __launch_bounds__(256) void attn_kernel(const float* __restrict__ qkv,
                                                   const unsigned* __restrict__ mask,
                                                   bf16* __restrict__ aos) {
  __shared__ float sq[4][256];
  __shared__ unsigned short nbr[4][2048];
  __shared__ int s_nn[4];
  int wv = threadIdx.x >> 6;
  int lane = threadIdx.x & 63;
  int bn = blockIdx.x * 4 + wv;
  int b = bn >> 11;
  if (lane == 0) s_nn[wv] = 0;
  *(float4*)&sq[wv][lane * 4] = *(const float4*)(qkv + (size_t)bn * 768 + lane * 4);
  __syncthreads();
  unsigned bits = mask[(size_t)bn * (N / 32) + lane];
  while (bits) {
    int bit = __ffs(bits) - 1;
    bits &= bits - 1;
    int p = atomicAdd(&s_nn[wv], 1);
    nbr[wv][p] = (unsigned short)(lane * 32 + bit);
  }
  __syncthreads();
  int nn = s_nn[wv];
  const float* base = qkv + (size_t)b * N * 768;
  float acc[4] = {0.f, 0.f, 0.f, 0.f};

  auto score4 = [&](int j, float* s) {
    const float* kr = base + (size_t)j * 768 + 256;
#pragma unroll
    for (int h = 0; h < 4; ++h) {
      float a = 0.f;
#pragma unroll
      for (int c = 0; c < DH; c += 4) {
        float4 kk = *(const float4*)(kr + h * DH + c);
        a += sq[wv][h * DH + c] * kk.x + sq[wv][h * DH + c + 1] * kk.y +
             sq[wv][h * DH + c + 2] * kk.z + sq[wv][h * DH + c + 3] * kk.w;
      }
      s[h] = a * 0.125f;
    }
  };

  if (nn <= 64) {
    float s[4] = {NEG_BIG, NEG_BIG, NEG_BIG, NEG_BIG};
    if (lane < nn) score4(nbr[wv][lane], s);
    float w[4], l[4];
#pragma unroll
    for (int h = 0; h < 4; ++h) {
      float m = s[h];
      for (int off = 32; off; off >>= 1) m = fmaxf(m, __shfl_down(m, off));
      m = __shfl(m, 0);
      float e = (lane < nn) ? __expf(s[h] - m) : 0.f;
      float ls = e;
      for (int off = 32; off; off >>= 1) ls += __shfl_down(ls, off);
      l[h] = __shfl(ls, 0);
      w[h] = e;
    }
    int i = 0;
    for (; i + 4 <= nn; i += 4) {
      int j0 = nbr[wv][i + 0], j1 = nbr[wv][i + 1];
      int j2 = nbr[wv][i + 2], j3 = nbr[wv][i + 3];
      const float* p0 = base + (size_t)j0 * 768 + 512;
      const float* p1 = base + (size_t)j1 * 768 + 512;
      const float* p2 = base + (size_t)j2 * 768 + 512;
      const float* p3 = base + (size_t)j3 * 768 + 512;
#pragma unroll
      for (int h = 0; h < 4; ++h) {
        acc[h] += __shfl(w[h], i + 0) * p0[h * DH + lane] +
                  __shfl(w[h], i + 1) * p1[h * DH + lane] +
                  __shfl(w[h], i + 2) * p2[h * DH + lane] +
                  __shfl(w[h], i + 3) * p3[h * DH + lane];
      }
    }
    for (; i < nn; ++i) {
      const float* p0 = base + (size_t)nbr[wv][i] * 768 + 512;
#pragma unroll
      for (int h = 0; h < 4; ++h) acc[h] += __shfl(w[h], i) * p0[h * DH + lane];
    }
#pragma unroll
    for (int h = 0; h < 4; ++h) acc[h] /= l[h];
  } else {
    float m[4] = {NEG_BIG, NEG_BIG, NEG_BIG, NEG_BIG};
    for (int i0 = 0; i0 < nn; i0 += 64) {
      float s[4] = {NEG_BIG, NEG_BIG, NEG_BIG, NEG_BIG};
      if (i0 + lane < nn) score4(nbr[wv][i0 + lane], s);
#pragma unroll
      for (int h = 0; h < 4; ++h) m[h] = fmaxf(m[h], s[h]);
    }
#pragma unroll
    for (int h = 0; h < 4; ++h) {
      for (int off = 32; off; off >>= 1) m[h] = fmaxf(m[h], __shfl_down(m[h], off));
      m[h] = __shfl(m[h], 0);
    }
    float l[4] = {0.f, 0.f, 0.f, 0.f};
    for (int i0 = 0; i0 < nn; i0 += 64) {
      float s[4] = {NEG_BIG, NEG_BIG, NEG_BIG, NEG_BIG};
      if (i0 + lane < nn) score4(nbr[wv][i0 + lane], s);
      float e[4];
#pragma unroll
      for (int h = 0; h < 4; ++h) {
        e[h] = (i0 + lane < nn) ? __expf(s[h] - m[h]) : 0.f;
        float ls = e[h];
        for (int off = 32; off; off >>= 1) ls += __shfl_down(ls, off);
        l[h] += __shfl(ls, 0);
      }
      int lim = min(64, nn - i0);
      for (int ii = 0; ii < lim; ++ii) {
        const float* p0 = base + (size_t)nbr[wv][i0 + ii] * 768 + 512;
#pragma unroll
        for (int h = 0; h < 4; ++h) acc[h] += __shfl(e[h], ii) * p0[h * DH + lane];
      }
    }
#pragma unroll
    for (int h = 0; h < 4; ++h) acc[h] /= l[h];
  }
#pragma unroll
  for (int h = 0; h < 4; ++h) {
    float a = acc[h];
    bf16 hi = (bf16)a;
    aos[(size_t)bn * 512 + h * DH + lane] = hi;
    aos[(size_t)bn * 512 + 256 + h * DH + lane] = (bf16)(a - (float)hi);
  }
}

// ---------------------------------------------------------------------------
// epilogue: u = x + proj + bo; out = LN(u)*gamma + beta
// ---------------------------------------------------------------------------
__global__ __launch_bounds__(64) void ln_kernel(const float* __restrict__ x,
                                                const float* __restrict__ proj,
                                                const float* __restrict__ bo,
                                                const float* __restrict__ gamma,
                                                const float* __restrict__ beta,
                                                float* __restrict__ out) {
  int row = blockIdx.x;
  int lane = threadIdx.x;
  size_t base = (size_t)row * D + lane * 4;
  float4 xv = *(const float4*)(x + base);
  float4 pv = *(const float4*)(proj + base);
  float4 bv = *(const float4*)(bo + lane * 4);
  float u0 = xv.x + pv.x + bv.x, u1 = xv.y + pv.y + bv.y;
  float u2 = xv.z + pv.z + bv.z, u3 = xv.w + pv.w + bv.w;
  float s = u0 + u1 + u2 + u3;
  for (int off = 32; off; off >>= 1) s += __shfl_down(s, off);
  s = __shfl(s, 0);
  float mean = s * (1.0f / D);
  float d0 = u0 - mean, d1 = u1 - mean, d2 = u2 - mean, d3 = u3 - mean;
  float ss = d0 * d0 + d1 * d1 + d2 * d2 + d3 * d3;
  for (int off = 32; off; off >>= 1) ss += __shfl_down(ss, off);
  ss = __shfl(ss, 0);
  float rstd = rsqrtf(ss * (1.0f / D) + 1e-5f);
  float4 gv = *(const float4*)(gamma + lane * 4);
  float4 be = *(const float4*)(beta + lane * 4);
  float4 o;
  o.x = d0 * rstd * gv.x + be.x;
  o.y = d1 * rstd * gv.y + be.y;
  o.z = d2 * rstd * gv.z + be.z;
  o.w = d3 * rstd * gv.w + be.w;
  *(float4*)(out + base) = o;
}

// ---------------------------------------------------------------------------
// Workspace (83,132,416 B total — the round-3-proven big layout):
//  phase A: XsN [0,12.58M) | sim [12.58M,79.69M) | topkb | mask | Wt (tail)
//  phase B (XsN+sim dead): XsRaw [0,8.39M) | qkv [8.39M,33.55M)
//                          aos [33.55M,41.94M) | proj [41.94M,50.33M)
// ---------------------------------------------------------------------------
extern "C" void kernel_launch(void* const* d_in, const int* in_sizes, int n_in,
                              void* d_out, int out_size, void* d_ws, size_t ws_size,
                              hipStream_t stream) {
  const float* x     = (const float*)d_in[0];
  const float* Wq    = (const float*)d_in[1];
  const float* Wk    = (const float*)d_in[2];
  const float* Wv    = (const float*)d_in[3];
  const float* Wo    = (const float*)d_in[4];
  const float* bo    = (const float*)d_in[5];
  const float* gamma = (const float*)d_in[6];
  const float* beta  = (const float*)d_in[7];
  float* out = (float*)d_out;

  char* ws = (char*)d_ws;
  bf16* XsN      = (bf16*)(ws);
  float* sim     = (float*)(ws + 12582912);
  int* topkb     = (int*)(ws + 79691776);
  unsigned* mask = (unsigned*)(ws + 79986688);
  bf16* Wt       = (bf16*)(ws + 82083840);
  bf16* XsRaw    = (bf16*)(ws);
  float* qkv     = (float*)(ws + 8388608);
  bf16* aos      = (bf16*)(ws + 33554432);
  float* proj    = (float*)(ws + 41943040);

  const int AMAP_SIM = PK6(0, 1, 0, 1, 0, 2);
  const int BMAP_SIM = PK6(0, 0, 1, 1, 2, 0);
  const int AMAP_2T  = PK3(0, 1, 0);
  const int BMAP_2T  = PK3(0, 0, 1);

  (void)hipMemsetAsync(mask, 0, (size_t)BATCH * N * (N / 32) * sizeof(unsigned), stream);
  prep_xn_w_kernel<<<9216, 64, 0, stream>>>(x, Wq, Wk, Wv, Wo, XsN, Wt);

  gemm_bt_kernel<<<dim3(136, 1, 4), 256, 0, stream>>>(
      XsN, XsN, sim, 768, 768, N, 24, AMAP_SIM, BMAP_SIM,
      (long)N * 768, (long)N * 768, (long)N * N, 1);
  topk_kernel<<<BATCH * N, 64, 0, stream>>>(sim, topkb);
  adj_kernel<<<(BATCH * N * TOPK + 255) / 256, 256, 0, stream>>>(topkb, mask);

  prep_raw_kernel<<<BATCH * N, 64, 0, stream>>>(x, XsRaw);
  gemm_bt_kernel<<<dim3(6, 64, 1), 256, 0, stream>>>(
      XsRaw, Wt, qkv, 512, 512, 768, 8, AMAP_2T, BMAP_2T, 0, 0, 0, 0);

  attn_kernel<<<(BATCH * N) / 4, 256, 0, stream>>>(qkv, mask, aos);

  gemm_bt_kernel<<<dim3(2, 64, 1), 256, 0, stream>>>(
      aos, Wt + (size_t)768 * 512, proj, 512, 512, D, 8, AMAP_2T, BMAP_2T, 0, 0, 0, 0);
  ln_kernel<<<BATCH * N, 64, 0, stream>>>(x, proj, bo, gamma, beta, out);
}

// Round 7
// 236.875 us; speedup vs baseline: 2.0486x; 1.1970x over previous
//
#include <hip/hip_runtime.h>
#include <hip/hip_bf16.h>
#include <math.h>

#define BATCH 4
#define N 2048
#define D 256
#define NH 4
#define DH 64
#define TOPK 9
#define NEG_BIG -1e30f

typedef __bf16 bf16;
typedef __bf16 bf16x8 __attribute__((ext_vector_type(8)));
typedef float f32x4 __attribute__((ext_vector_type(4)));

#define PK3(a,b,c) ((a) | ((b) << 2) | ((c) << 4))
#define PK6(a,b,c,d,e,f) ((a) | ((b) << 2) | ((c) << 4) | ((d) << 6) | ((e) << 8) | ((f) << 10))

// s_waitcnt with ONLY vmcnt=N (lgkmcnt=15/expcnt=7 = no wait). gfx9 encoding:
// vmcnt[3:0]@0, expcnt@4, lgkmcnt@8, vmcnt[5:4]@14.
#define WAITVM(Nc) __builtin_amdgcn_s_waitcnt((((Nc) & 0xf)) | (7u << 4) | (0xfu << 8) | ((((unsigned)(Nc)) >> 4) << 14))

__device__ __forceinline__ void async_cp16(const bf16* g, const bf16* l) {
  __builtin_amdgcn_global_load_lds(
      (const __attribute__((address_space(1))) void*)(uintptr_t)g,
      (__attribute__((address_space(3))) void*)(uintptr_t)l, 16, 0, 0);
}

// ---------------------------------------------------------------------------
// prep: blk<8192: x -> XsN (L2-norm, 3-way split, stride 768)
//       blk>=8192: W{q,k,v,o} -> Wt (transpose + 2-way split)
// ---------------------------------------------------------------------------
__global__ __launch_bounds__(64) void prep_xn_w_kernel(const float* __restrict__ x,
                                                       const float* __restrict__ Wq,
                                                       const float* __restrict__ Wk,
                                                       const float* __restrict__ Wv,
                                                       const float* __restrict__ Wo,
                                                       bf16* __restrict__ XsN,
                                                       bf16* __restrict__ Wt) {
  int blk = blockIdx.x;
  int lane = threadIdx.x;
  if (blk < 8192) {
    float4 v = *(const float4*)(x + (size_t)blk * D + lane * 4);
    float ss = v.x * v.x + v.y * v.y + v.z * v.z + v.w * v.w;
    for (int off = 32; off; off >>= 1) ss += __shfl_down(ss, off);
    ss = __shfl(ss, 0);
    float sc = 1.0f / fmaxf(sqrtf(ss), 1e-12f);
    float xs[4] = {v.x * sc, v.y * sc, v.z * sc, v.w * sc};
    bf16* o = XsN + (size_t)blk * 768 + lane * 4;
#pragma unroll
    for (int j = 0; j < 4; ++j) {
      float xv = xs[j];
      bf16 h = (bf16)xv;
      float r1 = xv - (float)h;
      bf16 m = (bf16)r1;
      o[j] = h;
      o[256 + j] = m;
      o[512 + j] = (bf16)(r1 - (float)m);
    }
  } else {
    int jj = blk - 8192;
    const float* W = (jj < 256) ? Wq : (jj < 512) ? Wk : (jj < 768) ? Wv : Wo;
    int j = jj & 255;
    bf16* dst = Wt + (size_t)jj * 512;
    for (int k = lane; k < 256; k += 64) {
      float w = W[(size_t)k * D + j];
      bf16 h = (bf16)w;
      dst[k] = h;
      dst[256 + k] = (bf16)(w - (float)h);
    }
  }
}

// prep phase 2: x -> XsRaw (2-way split, stride 512) — runs after sim is dead
__global__ __launch_bounds__(64) void prep_raw_kernel(const float* __restrict__ x,
                                                      bf16* __restrict__ XsRaw) {
  int row = blockIdx.x;
  int lane = threadIdx.x;
  float4 v = *(const float4*)(x + (size_t)row * D + lane * 4);
  float xs[4] = {v.x, v.y, v.z, v.w};
  bf16* o = XsRaw + (size_t)row * 512 + lane * 4;
#pragma unroll
  for (int j = 0; j < 4; ++j) {
    bf16 h = (bf16)xs[j];
    o[j] = h;
    o[256 + j] = (bf16)(xs[j] - (float)h);
  }
}

// ---------------------------------------------------------------------------
// MFMA GEMM, global_load_lds staging, LDS DOUBLE-BUFFER with raw s_barrier +
// fine-grained vmcnt(8) (no full drain — prefetch st+1 flies during compute st).
// mode 0: generic C = A@B^T, grid (Nc/128, M/128).
// mode 1: symmetric sim = A@A^T; compact triangular grid (136 pairs, z=batch),
//         mirror-write the transpose for off-diagonal tiles.
// ---------------------------------------------------------------------------
__global__ __launch_bounds__(256) void gemm_bt_kernel(const bf16* __restrict__ A,
                                                      const bf16* __restrict__ B,
                                                      float* __restrict__ C,
                                                      int lda, int ldb, int ldc,
                                                      int nsteps, int amap, int bmap,
                                                      long sA, long sB, long sC,
                                                      int mode) {
  __shared__ bf16 As[2][128 * 64];
  __shared__ bf16 Bs[2][128 * 64];
  int tid = threadIdx.x;
  int lane = tid & 63;
  int wv = tid >> 6;
  int wm = (wv >> 1) * 64;
  int wn = (wv & 1) * 64;
  int bx, by;
  if (mode) {  // triangular decode: enumerate (by, bx>=by)
    int t = blockIdx.x;
    by = 0;
    while (t >= 16 - by) { t -= 16 - by; ++by; }
    bx = by + t;
  } else {
    bx = blockIdx.x;
    by = blockIdx.y;
  }
  int row0 = by * 128;
  int col0 = bx * 128;
  int z = blockIdx.z;
  const bf16* Ab = A + (size_t)z * sA + (size_t)row0 * lda;
  const bf16* Bb = B + (size_t)z * sB + (size_t)col0 * ldb;
  float* Cb = C + (size_t)z * sC;

  int rbase = tid >> 3;
  int gperm = (tid & 7) ^ (rbase & 7);
  const bf16* ga0 = Ab + (size_t)rbase * lda + gperm * 8;
  const bf16* gb0 = Bb + (size_t)rbase * ldb + gperm * 8;
  int ldsoff = tid * 8;  // 16 B per thread

  int fr = lane & 15;
  int fq = (lane >> 4) * 8;

  f32x4 acc[4][4] = {};

  auto issue = [&](int st, int buf) {
    int ch = st >> 2;
    int aoff = (((amap >> (ch * 2)) & 3) << 8) | ((st & 3) << 6);
    int boff = (((bmap >> (ch * 2)) & 3) << 8) | ((st & 3) << 6);
#pragma unroll
    for (int q = 0; q < 4; ++q)
      async_cp16(ga0 + (size_t)q * 32 * lda + aoff, &As[buf][ldsoff + q * 2048]);
#pragma unroll
    for (int q = 0; q < 4; ++q)
      async_cp16(gb0 + (size_t)q * 32 * ldb + boff, &Bs[buf][ldsoff + q * 2048]);
  };

  issue(0, 0);
  for (int st = 0; st < nsteps; ++st) {
    int buf = st & 1;
    if (st + 1 < nsteps) {
      issue(st + 1, buf ^ 1);
      WAITVM(8);   // in-order retire: <=8 outstanding => buf st fully landed
    } else {
      WAITVM(0);
    }
    __builtin_amdgcn_s_barrier();  // all waves' staging for buf visible
#pragma unroll
    for (int ks = 0; ks < 64; ks += 32) {
      bf16x8 af[4], bfr[4];
#pragma unroll
      for (int mi = 0; mi < 4; ++mi) {
        int r = wm + mi * 16 + fr;
        int G = (ks + fq) >> 3;
        af[mi] = *(const bf16x8*)&As[buf][r * 64 + ((G ^ (r & 7)) << 3)];
      }
#pragma unroll
      for (int nj = 0; nj < 4; ++nj) {
        int r = wn + nj * 16 + fr;
        int G = (ks + fq) >> 3;
        bfr[nj] = *(const bf16x8*)&Bs[buf][r * 64 + ((G ^ (r & 7)) << 3)];
      }
#pragma unroll
      for (int mi = 0; mi < 4; ++mi)
#pragma unroll
        for (int nj = 0; nj < 4; ++nj)
          acc[mi][nj] = __builtin_amdgcn_mfma_f32_16x16x32_bf16(af[mi], bfr[nj], acc[mi][nj], 0, 0, 0);
    }
    __builtin_amdgcn_s_barrier();  // reads of buf done before st+2 overwrites it
  }

  int er = (lane >> 4) * 4;
  int ec = lane & 15;
#pragma unroll
  for (int mi = 0; mi < 4; ++mi)
#pragma unroll
    for (int nj = 0; nj < 4; ++nj) {
      int rb = row0 + wm + mi * 16 + er;
      int cb = col0 + wn + nj * 16 + ec;
#pragma unroll
      for (int reg = 0; reg < 4; ++reg)
        Cb[(size_t)(rb + reg) * ldc + cb] = acc[mi][nj][reg];
      if (mode && bx != by) {
#pragma unroll
        for (int reg = 0; reg < 4; ++reg)
          Cb[(size_t)cb * ldc + rb + reg] = acc[mi][nj][reg];
      }
    }
}

// ---------------------------------------------------------------------------
// top-9 per row by 9x extract-max (branch-free masked argmax in registers),
// fused adjacency write. One wave per row; mask pre-zeroed.
// Selection set identical to lax.top_k: (value desc, index asc) tie-break.
// ---------------------------------------------------------------------------
__global__ __launch_bounds__(64) void topk_adj_kernel(const float* __restrict__ sim,
                                                      unsigned* __restrict__ mask) {
  int row = blockIdx.x;
  int lane = threadIdx.x;
  int b = row >> 11, r = row & 2047;
  const float* srow = sim + (size_t)row * N;
  float v[32];
#pragma unroll
  for (int it = 0; it < 8; ++it) {
    float4 q = *(const float4*)(srow + it * 256 + lane * 4);
    v[it * 4 + 0] = q.x; v[it * 4 + 1] = q.y;
    v[it * 4 + 2] = q.z; v[it * 4 + 3] = q.w;
  }
  unsigned removed = 0;
  for (int rs = 0; rs < TOPK; ++rs) {
    float m = -3e38f;
    int mi = 0;
#pragma unroll
    for (int i = 0; i < 32; ++i) {
      float vv = ((removed >> i) & 1u) ? -3e38f : v[i];
      if (vv > m) { m = vv; mi = i; }  // ascending i = ascending global idx
    }
    int gidx = ((mi >> 2) << 8) + lane * 4 + (mi & 3);
    for (int off = 32; off; off >>= 1) {
      float om = __shfl_down(m, off);
      int og = __shfl_down(gidx, off);
      if (om > m || (om == m && og < gidx)) { m = om; gidx = og; }
    }
    gidx = __shfl(gidx, 0);
    if (((gidx >> 2) & 63) == lane)
      removed |= 1u << (((gidx >> 8) << 2) | (gidx & 3));
    if (lane == 0) {
      atomicOr(&mask[(size_t)row * 64 + (gidx >> 5)], 1u << (gidx & 31));
      atomicOr(&mask[(((size_t)b << 11) + gidx) * 64 + (r >> 5)], 1u << (r & 31));
    }
  }
}

// ---------------------------------------------------------------------------
// sparse attention: 4 waves/block, one (b,n) row per wave; writes bf16-split
// aos (stride 512) directly.
// ---------------------------------------------------------------------------
__global__ __launch_bounds__(256) void attn_kernel(const float* __restrict__ qkv,
                                                   const unsigned* __restrict__ mask,
                                                   bf16* __restrict__ aos) {
  __shared__ float sq[4][256];
  __shared__ unsigned short nbr[4][2048];
  __shared__ int s_nn[4];
  int wv = threadIdx.x >> 6;
  int lane = threadIdx.x & 63;
  int bn = blockIdx.x * 4 + wv;
  int b = bn >> 11;
  if (lane == 0) s_nn[wv] = 0;
  *(float4*)&sq[wv][lane * 4] = *(const float4*)(qkv + (size_t)bn * 768 + lane * 4);
  __syncthreads();
  unsigned bits = mask[(size_t)bn * (N / 32) + lane];
  while (bits) {
    int bit = __ffs(bits) - 1;
    bits &= bits - 1;
    int p = atomicAdd(&s_nn[wv], 1);
    nbr[wv][p] = (unsigned short)(lane * 32 + bit);
  }
  __syncthreads();
  int nn = s_nn[wv];
  const float* base = qkv + (size_t)b * N * 768;
  float acc[4] = {0.f, 0.f, 0.f, 0.f};

  auto score4 = [&](int j, float* s) {
    const float* kr = base + (size_t)j * 768 + 256;
#pragma unroll
    for (int h = 0; h < 4; ++h) {
      float a = 0.f;
#pragma unroll
      for (int c = 0; c < DH; c += 4) {
        float4 kk = *(const float4*)(kr + h * DH + c);
        a += sq[wv][h * DH + c] * kk.x + sq[wv][h * DH + c + 1] * kk.y +
             sq[wv][h * DH + c + 2] * kk.z + sq[wv][h * DH + c + 3] * kk.w;
      }
      s[h] = a * 0.125f;
    }
  };

  if (nn <= 64) {
    float s[4] = {NEG_BIG, NEG_BIG, NEG_BIG, NEG_BIG};
    if (lane < nn) score4(nbr[wv][lane], s);
    float w[4], l[4];
#pragma unroll
    for (int h = 0; h < 4; ++h) {
      float m = s[h];
      for (int off = 32; off; off >>= 1) m = fmaxf(m, __shfl_down(m, off));
      m = __shfl(m, 0);
      float e = (lane < nn) ? __expf(s[h] - m) : 0.f;
      float ls = e;
      for (int off = 32; off; off >>= 1) ls += __shfl_down(ls, off);
      l[h] = __shfl(ls, 0);
      w[h] = e;
    }
    int i = 0;
    for (; i + 4 <= nn; i += 4) {
      int j0 = nbr[wv][i + 0], j1 = nbr[wv][i + 1];
      int j2 = nbr[wv][i + 2], j3 = nbr[wv][i + 3];
      const float* p0 = base + (size_t)j0 * 768 + 512;
      const float* p1 = base + (size_t)j1 * 768 + 512;
      const float* p2 = base + (size_t)j2 * 768 + 512;
      const float* p3 = base + (size_t)j3 * 768 + 512;
#pragma unroll
      for (int h = 0; h < 4; ++h) {
        acc[h] += __shfl(w[h], i + 0) * p0[h * DH + lane] +
                  __shfl(w[h], i + 1) * p1[h * DH + lane] +
                  __shfl(w[h], i + 2) * p2[h * DH + lane] +
                  __shfl(w[h], i + 3) * p3[h * DH + lane];
      }
    }
    for (; i < nn; ++i) {
      const float* p0 = base + (size_t)nbr[wv][i] * 768 + 512;
#pragma unroll
      for (int h = 0; h < 4; ++h) acc[h] += __shfl(w[h], i) * p0[h * DH + lane];
    }
#pragma unroll
    for (int h = 0; h < 4; ++h) acc[h] /= l[h];
  } else {
    float m[4] = {NEG_BIG, NEG_BIG, NEG_BIG, NEG_BIG};
    for (int i0 = 0; i0 < nn; i0 += 64) {
      float s[4] = {NEG_BIG, NEG_BIG, NEG_BIG, NEG_BIG};
      if (i0 + lane < nn) score4(nbr[wv][i0 + lane], s);
#pragma unroll
      for (int h = 0; h < 4; ++h) m[h] = fmaxf(m[h], s[h]);
    }
#pragma unroll
    for (int h = 0; h < 4; ++h) {
      for (int off = 32; off; off >>= 1) m[h] = fmaxf(m[h], __shfl_down(m[h], off));
      m[h] = __shfl(m[h], 0);
    }
    float l[4] = {0.f, 0.f, 0.f, 0.f};
    for (int i0 = 0; i0 < nn; i0 += 64) {
      float s[4] = {NEG_BIG, NEG_BIG, NEG_BIG, NEG_BIG};
      if (i0 + lane < nn) score4(nbr[wv][i0 + lane], s);
      float e[4];
#pragma unroll
      for (int h = 0; h < 4; ++h) {
        e[h] = (i0 + lane < nn) ? __expf(s[h] - m[h]) : 0.f;
        float ls = e[h];
        for (int off = 32; off; off >>= 1) ls += __shfl_down(ls, off);
        l[h] += __shfl(ls, 0);
      }
      int lim = min(64, nn - i0);
      for (int ii = 0; ii < lim; ++ii) {
        const float* p0 = base + (size_t)nbr[wv][i0 + ii] * 768 + 512;
#pragma unroll
        for (int h = 0; h < 4; ++h) acc[h] += __shfl(e[h], ii) * p0[h * DH + lane];
      }
    }
#pragma unroll
    for (int h = 0; h < 4; ++h) acc[h] /= l[h];
  }
#pragma unroll
  for (int h = 0; h < 4; ++h) {
    float a = acc[h];
    bf16 hi = (bf16)a;
    aos[(size_t)bn * 512 + h * DH + lane] = hi;
    aos[(size_t)bn * 512 + 256 + h * DH + lane] = (bf16)(a - (float)hi);
  }
}

// ---------------------------------------------------------------------------
// epilogue: u = x + proj + bo; out = LN(u)*gamma + beta
// ---------------------------------------------------------------------------
__global__ __launch_bounds__(64) void ln_kernel(const float* __restrict__ x,
                                                const float* __restrict__ proj,
                                                const float* __restrict__ bo,
                                                const float* __restrict__ gamma,
                                                const float* __restrict__ beta,
                                                float* __restrict__ out) {
  int row = blockIdx.x;
  int lane = threadIdx.x;
  size_t base = (size_t)row * D + lane * 4;
  float4 xv = *(const float4*)(x + base);
  float4 pv = *(const float4*)(proj + base);
  float4 bv = *(const float4*)(bo + lane * 4);
  float u0 = xv.x + pv.x + bv.x, u1 = xv.y + pv.y + bv.y;
  float u2 = xv.z + pv.z + bv.z, u3 = xv.w + pv.w + bv.w;
  float s = u0 + u1 + u2 + u3;
  for (int off = 32; off; off >>= 1) s += __shfl_down(s, off);
  s = __shfl(s, 0);
  float mean = s * (1.0f / D);
  float d0 = u0 - mean, d1 = u1 - mean, d2 = u2 - mean, d3 = u3 - mean;
  float ss = d0 * d0 + d1 * d1 + d2 * d2 + d3 * d3;
  for (int off = 32; off; off >>= 1) ss += __shfl_down(ss, off);
  ss = __shfl(ss, 0);
  float rstd = rsqrtf(ss * (1.0f / D) + 1e-5f);
  float4 gv = *(const float4*)(gamma + lane * 4);
  float4 be = *(const float4*)(beta + lane * 4);
  float4 o;
  o.x = d0 * rstd * gv.x + be.x;
  o.y = d1 * rstd * gv.y + be.y;
  o.z = d2 * rstd * gv.z + be.z;
  o.w = d3 * rstd * gv.w + be.w;
  *(float4*)(out + base) = o;
}

// ---------------------------------------------------------------------------
// Workspace (83,132,416 B total — round-3-proven big layout):
//  phase A: XsN [0,12.58M) | sim [12.58M,79.69M) | (topkb slot unused) | mask | Wt
//  phase B (XsN+sim dead): XsRaw [0,8.39M) | qkv [8.39M,33.55M)
//                          aos [33.55M,41.94M) | proj [41.94M,50.33M)
// ---------------------------------------------------------------------------
extern "C" void kernel_launch(void* const* d_in, const int* in_sizes, int n_in,
                              void* d_out, int out_size, void* d_ws, size_t ws_size,
                              hipStream_t stream) {
  const float* x     = (const float*)d_in[0];
  const float* Wq    = (const float*)d_in[1];
  const float* Wk    = (const float*)d_in[2];
  const float* Wv    = (const float*)d_in[3];
  const float* Wo    = (const float*)d_in[4];
  const float* bo    = (const float*)d_in[5];
  const float* gamma = (const float*)d_in[6];
  const float* beta  = (const float*)d_in[7];
  float* out = (float*)d_out;

  char* ws = (char*)d_ws;
  bf16* XsN      = (bf16*)(ws);
  float* sim     = (float*)(ws + 12582912);
  unsigned* mask = (unsigned*)(ws + 79986688);
  bf16* Wt       = (bf16*)(ws + 82083840);
  bf16* XsRaw    = (bf16*)(ws);
  float* qkv     = (float*)(ws + 8388608);
  bf16* aos      = (bf16*)(ws + 33554432);
  float* proj    = (float*)(ws + 41943040);

  const int AMAP_SIM = PK6(0, 1, 0, 1, 0, 2);
  const int BMAP_SIM = PK6(0, 0, 1, 1, 2, 0);
  const int AMAP_2T  = PK3(0, 1, 0);
  const int BMAP_2T  = PK3(0, 0, 1);

  (void)hipMemsetAsync(mask, 0, (size_t)BATCH * N * (N / 32) * sizeof(unsigned), stream);
  prep_xn_w_kernel<<<9216, 64, 0, stream>>>(x, Wq, Wk, Wv, Wo, XsN, Wt);

  gemm_bt_kernel<<<dim3(136, 1, 4), 256, 0, stream>>>(
      XsN, XsN, sim, 768, 768, N, 24, AMAP_SIM, BMAP_SIM,
      (long)N * 768, (long)N * 768, (long)N * N, 1);
  topk_adj_kernel<<<BATCH * N, 64, 0, stream>>>(sim, mask);

  prep_raw_kernel<<<BATCH * N, 64, 0, stream>>>(x, XsRaw);
  gemm_bt_kernel<<<dim3(6, 64, 1), 256, 0, stream>>>(
      XsRaw, Wt, qkv, 512, 512, 768, 8, AMAP_2T, BMAP_2T, 0, 0, 0, 0);

  attn_kernel<<<(BATCH * N) / 4, 256, 0, stream>>>(qkv, mask, aos);

  gemm_bt_kernel<<<dim3(2, 64, 1), 256, 0, stream>>>(
      aos, Wt + (size_t)768 * 512, proj, 512, 512, D, 8, AMAP_2T, BMAP_2T, 0, 0, 0, 0);
  ln_kernel<<<BATCH * N, 64, 0, stream>>>(x, proj, bo, gamma, beta, out);
}

// Round 8
// 223.531 us; speedup vs baseline: 2.1709x; 1.0597x over previous
//
#include <hip/hip_runtime.h>
#include <hip/hip_bf16.h>
#include <math.h>

#define BATCH 4
#define N 2048
#define D 256
#define NH 4
#define DH 64
#define TOPK 9
#define NEG_BIG -1e30f

typedef __bf16 bf16;
typedef __bf16 bf16x8 __attribute__((ext_vector_type(8)));
typedef float f32x4 __attribute__((ext_vector_type(4)));

#define PK3(a,b,c) ((a) | ((b) << 2) | ((c) << 4))
#define PK6(a,b,c,d,e,f) ((a) | ((b) << 2) | ((c) << 4) | ((d) << 6) | ((e) << 8) | ((f) << 10))

// s_waitcnt with ONLY vmcnt=N (lgkmcnt=15/expcnt=7 = no wait). gfx9 encoding:
// vmcnt[3:0]@0, expcnt@4, lgkmcnt@8, vmcnt[5:4]@14.
#define WAITVM(Nc) __builtin_amdgcn_s_waitcnt((((Nc) & 0xf)) | (7u << 4) | (0xfu << 8) | ((((unsigned)(Nc)) >> 4) << 14))

__device__ __forceinline__ void async_cp16(const bf16* g, const bf16* l) {
  __builtin_amdgcn_global_load_lds(
      (const __attribute__((address_space(1))) void*)(uintptr_t)g,
      (__attribute__((address_space(3))) void*)(uintptr_t)l, 16, 0, 0);
}

// ---------------------------------------------------------------------------
// prep: blk<8192: x -> XsN (L2-norm, 3-way split, stride 768)
//       blk>=8192: W{q,k,v,o} -> Wt (transpose + 2-way split)
// ---------------------------------------------------------------------------
__global__ __launch_bounds__(64) void prep_xn_w_kernel(const float* __restrict__ x,
                                                       const float* __restrict__ Wq,
                                                       const float* __restrict__ Wk,
                                                       const float* __restrict__ Wv,
                                                       const float* __restrict__ Wo,
                                                       bf16* __restrict__ XsN,
                                                       bf16* __restrict__ Wt) {
  int blk = blockIdx.x;
  int lane = threadIdx.x;
  if (blk < 8192) {
    float4 v = *(const float4*)(x + (size_t)blk * D + lane * 4);
    float ss = v.x * v.x + v.y * v.y + v.z * v.z + v.w * v.w;
    for (int off = 32; off; off >>= 1) ss += __shfl_down(ss, off);
    ss = __shfl(ss, 0);
    float sc = 1.0f / fmaxf(sqrtf(ss), 1e-12f);
    float xs[4] = {v.x * sc, v.y * sc, v.z * sc, v.w * sc};
    bf16* o = XsN + (size_t)blk * 768 + lane * 4;
#pragma unroll
    for (int j = 0; j < 4; ++j) {
      float xv = xs[j];
      bf16 h = (bf16)xv;
      float r1 = xv - (float)h;
      bf16 m = (bf16)r1;
      o[j] = h;
      o[256 + j] = m;
      o[512 + j] = (bf16)(r1 - (float)m);
    }
  } else {
    int jj = blk - 8192;
    const float* W = (jj < 256) ? Wq : (jj < 512) ? Wk : (jj < 768) ? Wv : Wo;
    int j = jj & 255;
    bf16* dst = Wt + (size_t)jj * 512;
    for (int k = lane; k < 256; k += 64) {
      float w = W[(size_t)k * D + j];
      bf16 h = (bf16)w;
      dst[k] = h;
      dst[256 + k] = (bf16)(w - (float)h);
    }
  }
}

// prep phase 2: x -> XsRaw (2-way split, stride 512) — runs after sim is dead
__global__ __launch_bounds__(64) void prep_raw_kernel(const float* __restrict__ x,
                                                      bf16* __restrict__ XsRaw) {
  int row = blockIdx.x;
  int lane = threadIdx.x;
  float4 v = *(const float4*)(x + (size_t)row * D + lane * 4);
  float xs[4] = {v.x, v.y, v.z, v.w};
  bf16* o = XsRaw + (size_t)row * 512 + lane * 4;
#pragma unroll
  for (int j = 0; j < 4; ++j) {
    bf16 h = (bf16)xs[j];
    o[j] = h;
    o[256 + j] = (bf16)(xs[j] - (float)h);
  }
}

// ---------------------------------------------------------------------------
// MFMA GEMM, global_load_lds staging, LDS double-buffer, raw s_barrier +
// fine-grained vmcnt(8).
// mode 0: generic C = A@B^T, grid (Nc/128, M/128, batches).
// mode 1: symmetric sim = A@A^T, grid (544,1,1) with XCD-AWARE decode:
//   xcd = g&7 handles batch z=xcd>>1, triangle-half h=xcd&1, slot=g>>3;
//   pair = h*68+slot -> (by, bx>=by). Each XCD's panel set (3.1 MB) stays
//   L2-resident. C written with nontemporal stores (incl. mirror).
// ---------------------------------------------------------------------------
__global__ __launch_bounds__(256) void gemm_bt_kernel(const bf16* __restrict__ A,
                                                      const bf16* __restrict__ B,
                                                      float* __restrict__ C,
                                                      int lda, int ldb, int ldc,
                                                      int nsteps, int amap, int bmap,
                                                      long sA, long sB, long sC,
                                                      int mode) {
  __shared__ bf16 As[2][128 * 64];
  __shared__ bf16 Bs[2][128 * 64];
  int tid = threadIdx.x;
  int lane = tid & 63;
  int wv = tid >> 6;
  int wm = (wv >> 1) * 64;
  int wn = (wv & 1) * 64;
  int bx, by, z;
  if (mode) {  // XCD-aware triangular decode
    int g = blockIdx.x;
    int xcd = g & 7;
    int slot = g >> 3;          // 0..67
    z = xcd >> 1;
    int t = (xcd & 1) * 68 + slot;  // pair 0..135
    by = 0;
    while (t >= 16 - by) { t -= 16 - by; ++by; }
    bx = by + t;
  } else {
    bx = blockIdx.x;
    by = blockIdx.y;
    z = blockIdx.z;
  }
  int row0 = by * 128;
  int col0 = bx * 128;
  const bf16* Ab = A + (size_t)z * sA + (size_t)row0 * lda;
  const bf16* Bb = B + (size_t)z * sB + (size_t)col0 * ldb;
  float* Cb = C + (size_t)z * sC;

  int rbase = tid >> 3;
  int gperm = (tid & 7) ^ (rbase & 7);
  const bf16* ga0 = Ab + (size_t)rbase * lda + gperm * 8;
  const bf16* gb0 = Bb + (size_t)rbase * ldb + gperm * 8;
  int ldsoff = tid * 8;  // 16 B per thread

  int fr = lane & 15;
  int fq = (lane >> 4) * 8;

  f32x4 acc[4][4] = {};

  auto issue = [&](int st, int buf) {
    int ch = st >> 2;
    int aoff = (((amap >> (ch * 2)) & 3) << 8) | ((st & 3) << 6);
    int boff = (((bmap >> (ch * 2)) & 3) << 8) | ((st & 3) << 6);
#pragma unroll
    for (int q = 0; q < 4; ++q)
      async_cp16(ga0 + (size_t)q * 32 * lda + aoff, &As[buf][ldsoff + q * 2048]);
#pragma unroll
    for (int q = 0; q < 4; ++q)
      async_cp16(gb0 + (size_t)q * 32 * ldb + boff, &Bs[buf][ldsoff + q * 2048]);
  };

  issue(0, 0);
  for (int st = 0; st < nsteps; ++st) {
    int buf = st & 1;
    if (st + 1 < nsteps) {
      issue(st + 1, buf ^ 1);
      WAITVM(8);   // in-order retire: <=8 outstanding => buf st fully landed
    } else {
      WAITVM(0);
    }
    __builtin_amdgcn_s_barrier();  // all waves' staging for buf visible
#pragma unroll
    for (int ks = 0; ks < 64; ks += 32) {
      bf16x8 af[4], bfr[4];
#pragma unroll
      for (int mi = 0; mi < 4; ++mi) {
        int r = wm + mi * 16 + fr;
        int G = (ks + fq) >> 3;
        af[mi] = *(const bf16x8*)&As[buf][r * 64 + ((G ^ (r & 7)) << 3)];
      }
#pragma unroll
      for (int nj = 0; nj < 4; ++nj) {
        int r = wn + nj * 16 + fr;
        int G = (ks + fq) >> 3;
        bfr[nj] = *(const bf16x8*)&Bs[buf][r * 64 + ((G ^ (r & 7)) << 3)];
      }
#pragma unroll
      for (int mi = 0; mi < 4; ++mi)
#pragma unroll
        for (int nj = 0; nj < 4; ++nj)
          acc[mi][nj] = __builtin_amdgcn_mfma_f32_16x16x32_bf16(af[mi], bfr[nj], acc[mi][nj], 0, 0, 0);
    }
    __builtin_amdgcn_s_barrier();  // reads of buf done before st+2 overwrites it
  }

  int er = (lane >> 4) * 4;
  int ec = lane & 15;
#pragma unroll
  for (int mi = 0; mi < 4; ++mi)
#pragma unroll
    for (int nj = 0; nj < 4; ++nj) {
      int rb = row0 + wm + mi * 16 + er;
      int cb = col0 + wn + nj * 16 + ec;
      if (mode) {
#pragma unroll
        for (int reg = 0; reg < 4; ++reg)
          __builtin_nontemporal_store(acc[mi][nj][reg],
                                      &Cb[(size_t)(rb + reg) * ldc + cb]);
        if (bx != by) {
#pragma unroll
          for (int reg = 0; reg < 4; ++reg)
            __builtin_nontemporal_store(acc[mi][nj][reg],
                                        &Cb[(size_t)cb * ldc + rb + reg]);
        }
      } else {
#pragma unroll
        for (int reg = 0; reg < 4; ++reg)
          Cb[(size_t)(rb + reg) * ldc + cb] = acc[mi][nj][reg];
      }
    }
}

// ---------------------------------------------------------------------------
// top-9 per row by 9x extract-max (branch-free masked argmax in registers),
// fused adjacency write. One wave per row; mask pre-zeroed.
// Selection set identical to lax.top_k: (value desc, index asc) tie-break.
// ---------------------------------------------------------------------------
__global__ __launch_bounds__(64) void topk_adj_kernel(const float* __restrict__ sim,
                                                      unsigned* __restrict__ mask) {
  int row = blockIdx.x;
  int lane = threadIdx.x;
  int b = row >> 11, r = row & 2047;
  const float* srow = sim + (size_t)row * N;
  float v[32];
#pragma unroll
  for (int it = 0; it < 8; ++it) {
    float4 q = *(const float4*)(srow + it * 256 + lane * 4);
    v[it * 4 + 0] = q.x; v[it * 4 + 1] = q.y;
    v[it * 4 + 2] = q.z; v[it * 4 + 3] = q.w;
  }
  unsigned removed = 0;
  for (int rs = 0; rs < TOPK; ++rs) {
    float m = -3e38f;
    int mi = 0;
#pragma unroll
    for (int i = 0; i < 32; ++i) {
      float vv = ((removed >> i) & 1u) ? -3e38f : v[i];
      if (vv > m) { m = vv; mi = i; }  // ascending i = ascending global idx
    }
    int gidx = ((mi >> 2) << 8) + lane * 4 + (mi & 3);
    for (int off = 32; off; off >>= 1) {
      float om = __shfl_down(m, off);
      int og = __shfl_down(gidx, off);
      if (om > m || (om == m && og < gidx)) { m = om; gidx = og; }
    }
    gidx = __shfl(gidx, 0);
    if (((gidx >> 2) & 63) == lane)
      removed |= 1u << (((gidx >> 8) << 2) | (gidx & 3));
    if (lane == 0) {
      atomicOr(&mask[(size_t)row * 64 + (gidx >> 5)], 1u << (gidx & 31));
      atomicOr(&mask[(((size_t)b << 11) + gidx) * 64 + (r >> 5)], 1u << (r & 31));
    }
  }
}

// ---------------------------------------------------------------------------
// sparse attention: 4 waves/block, one (b,n) row per wave; writes bf16-split
// aos (stride 512) directly.
// ---------------------------------------------------------------------------
__global__ __launch_bounds__(256) void attn_kernel(const float* __restrict__ qkv,
                                                   const unsigned* __restrict__ mask,
                                                   bf16* __restrict__ aos) {
  __shared__ float sq[4][256];
  __shared__ unsigned short nbr[4][2048];
  __shared__ int s_nn[4];
  int wv = threadIdx.x >> 6;
  int lane = threadIdx.x & 63;
  int bn = blockIdx.x * 4 + wv;
  int b = bn >> 11;
  if (lane == 0) s_nn[wv] = 0;
  *(float4*)&sq[wv][lane * 4] = *(const float4*)(qkv + (size_t)bn * 768 + lane * 4);
  __syncthreads();
  unsigned bits = mask[(size_t)bn * (N / 32) + lane];
  while (bits) {
    int bit = __ffs(bits) - 1;
    bits &= bits - 1;
    int p = atomicAdd(&s_nn[wv], 1);
    nbr[wv][p] = (unsigned short)(lane * 32 + bit);
  }
  __syncthreads();
  int nn = s_nn[wv];
  const float* base = qkv + (size_t)b * N * 768;
  float acc[4] = {0.f, 0.f, 0.f, 0.f};

  auto score4 = [&](int j, float* s) {
    const float* kr = base + (size_t)j * 768 + 256;
#pragma unroll
    for (int h = 0; h < 4; ++h) {
      float a = 0.f;
#pragma unroll
      for (int c = 0; c < DH; c += 4) {
        float4 kk = *(const float4*)(kr + h * DH + c);
        a += sq[wv][h * DH + c] * kk.x + sq[wv][h * DH + c + 1] * kk.y +
             sq[wv][h * DH + c + 2] * kk.z + sq[wv][h * DH + c + 3] * kk.w;
      }
      s[h] = a * 0.125f;
    }
  };

  if (nn <= 64) {
    float s[4] = {NEG_BIG, NEG_BIG, NEG_BIG, NEG_BIG};
    if (lane < nn) score4(nbr[wv][lane], s);
    float w[4], l[4];
#pragma unroll
    for (int h = 0; h < 4; ++h) {
      float m = s[h];
      for (int off = 32; off; off >>= 1) m = fmaxf(m, __shfl_down(m, off));
      m = __shfl(m, 0);
      float e = (lane < nn) ? __expf(s[h] - m) : 0.f;
      float ls = e;
      for (int off = 32; off; off >>= 1) ls += __shfl_down(ls, off);
      l[h] = __shfl(ls, 0);
      w[h] = e;
    }
    int i = 0;
    for (; i + 4 <= nn; i += 4) {
      int j0 = nbr[wv][i + 0], j1 = nbr[wv][i + 1];
      int j2 = nbr[wv][i + 2], j3 = nbr[wv][i + 3];
      const float* p0 = base + (size_t)j0 * 768 + 512;
      const float* p1 = base + (size_t)j1 * 768 + 512;
      const float* p2 = base + (size_t)j2 * 768 + 512;
      const float* p3 = base + (size_t)j3 * 768 + 512;
#pragma unroll
      for (int h = 0; h < 4; ++h) {
        acc[h] += __shfl(w[h], i + 0) * p0[h * DH + lane] +
                  __shfl(w[h], i + 1) * p1[h * DH + lane] +
                  __shfl(w[h], i + 2) * p2[h * DH + lane] +
                  __shfl(w[h], i + 3) * p3[h * DH + lane];
      }
    }
    for (; i < nn; ++i) {
      const float* p0 = base + (size_t)nbr[wv][i] * 768 + 512;
#pragma unroll
      for (int h = 0; h < 4; ++h) acc[h] += __shfl(w[h], i) * p0[h * DH + lane];
    }
#pragma unroll
    for (int h = 0; h < 4; ++h) acc[h] /= l[h];
  } else {
    float m[4] = {NEG_BIG, NEG_BIG, NEG_BIG, NEG_BIG};
    for (int i0 = 0; i0 < nn; i0 += 64) {
      float s[4] = {NEG_BIG, NEG_BIG, NEG_BIG, NEG_BIG};
      if (i0 + lane < nn) score4(nbr[wv][i0 + lane], s);
#pragma unroll
      for (int h = 0; h < 4; ++h) m[h] = fmaxf(m[h], s[h]);
    }
#pragma unroll
    for (int h = 0; h < 4; ++h) {
      for (int off = 32; off; off >>= 1) m[h] = fmaxf(m[h], __shfl_down(m[h], off));
      m[h] = __shfl(m[h], 0);
    }
    float l[4] = {0.f, 0.f, 0.f, 0.f};
    for (int i0 = 0; i0 < nn; i0 += 64) {
      float s[4] = {NEG_BIG, NEG_BIG, NEG_BIG, NEG_BIG};
      if (i0 + lane < nn) score4(nbr[wv][i0 + lane], s);
      float e[4];
#pragma unroll
      for (int h = 0; h < 4; ++h) {
        e[h] = (i0 + lane < nn) ? __expf(s[h] - m[h]) : 0.f;
        float ls = e[h];
        for (int off = 32; off; off >>= 1) ls += __shfl_down(ls, off);
        l[h] += __shfl(ls, 0);
      }
      int lim = min(64, nn - i0);
      for (int ii = 0; ii < lim; ++ii) {
        const float* p0 = base + (size_t)nbr[wv][i0 + ii] * 768 + 512;
#pragma unroll
        for (int h = 0; h < 4; ++h) acc[h] += __shfl(e[h], ii) * p0[h * DH + lane];
      }
    }
#pragma unroll
    for (int h = 0; h < 4; ++h) acc[h] /= l[h];
  }
#pragma unroll
  for (int h = 0; h < 4; ++h) {
    float a = acc[h];
    bf16 hi = (bf16)a;
    aos[(size_t)bn * 512 + h * DH + lane] = hi;
    aos[(size_t)bn * 512 + 256 + h * DH + lane] = (bf16)(a - (float)hi);
  }
}

// ---------------------------------------------------------------------------
// epilogue: u = x + proj + bo; out = LN(u)*gamma + beta
// ---------------------------------------------------------------------------
__global__ __launch_bounds__(64) void ln_kernel(const float* __restrict__ x,
                                                const float* __restrict__ proj,
                                                const float* __restrict__ bo,
                                                const float* __restrict__ gamma,
                                                const float* __restrict__ beta,
                                                float* __restrict__ out) {
  int row = blockIdx.x;
  int lane = threadIdx.x;
  size_t base = (size_t)row * D + lane * 4;
  float4 xv = *(const float4*)(x + base);
  float4 pv = *(const float4*)(proj + base);
  float4 bv = *(const float4*)(bo + lane * 4);
  float u0 = xv.x + pv.x + bv.x, u1 = xv.y + pv.y + bv.y;
  float u2 = xv.z + pv.z + bv.z, u3 = xv.w + pv.w + bv.w;
  float s = u0 + u1 + u2 + u3;
  for (int off = 32; off; off >>= 1) s += __shfl_down(s, off);
  s = __shfl(s, 0);
  float mean = s * (1.0f / D);
  float d0 = u0 - mean, d1 = u1 - mean, d2 = u2 - mean, d3 = u3 - mean;
  float ss = d0 * d0 + d1 * d1 + d2 * d2 + d3 * d3;
  for (int off = 32; off; off >>= 1) ss += __shfl_down(ss, off);
  ss = __shfl(ss, 0);
  float rstd = rsqrtf(ss * (1.0f / D) + 1e-5f);
  float4 gv = *(const float4*)(gamma + lane * 4);
  float4 be = *(const float4*)(beta + lane * 4);
  float4 o;
  o.x = d0 * rstd * gv.x + be.x;
  o.y = d1 * rstd * gv.y + be.y;
  o.z = d2 * rstd * gv.z + be.z;
  o.w = d3 * rstd * gv.w + be.w;
  *(float4*)(out + base) = o;
}

// ---------------------------------------------------------------------------
// Workspace (83,132,416 B total — round-3-proven big layout):
//  phase A: XsN [0,12.58M) | sim [12.58M,79.69M) | mask | Wt
//  phase B (XsN+sim dead): XsRaw [0,8.39M) | qkv [8.39M,33.55M)
//                          aos [33.55M,41.94M) | proj [41.94M,50.33M)
// ---------------------------------------------------------------------------
extern "C" void kernel_launch(void* const* d_in, const int* in_sizes, int n_in,
                              void* d_out, int out_size, void* d_ws, size_t ws_size,
                              hipStream_t stream) {
  const float* x     = (const float*)d_in[0];
  const float* Wq    = (const float*)d_in[1];
  const float* Wk    = (const float*)d_in[2];
  const float* Wv    = (const float*)d_in[3];
  const float* Wo    = (const float*)d_in[4];
  const float* bo    = (const float*)d_in[5];
  const float* gamma = (const float*)d_in[6];
  const float* beta  = (const float*)d_in[7];
  float* out = (float*)d_out;

  char* ws = (char*)d_ws;
  bf16* XsN      = (bf16*)(ws);
  float* sim     = (float*)(ws + 12582912);
  unsigned* mask = (unsigned*)(ws + 79986688);
  bf16* Wt       = (bf16*)(ws + 82083840);
  bf16* XsRaw    = (bf16*)(ws);
  float* qkv     = (float*)(ws + 8388608);
  bf16* aos      = (bf16*)(ws + 33554432);
  float* proj    = (float*)(ws + 41943040);

  const int AMAP_SIM = PK6(0, 1, 0, 1, 0, 2);
  const int BMAP_SIM = PK6(0, 0, 1, 1, 2, 0);
  const int AMAP_2T  = PK3(0, 1, 0);
  const int BMAP_2T  = PK3(0, 0, 1);

  (void)hipMemsetAsync(mask, 0, (size_t)BATCH * N * (N / 32) * sizeof(unsigned), stream);
  prep_xn_w_kernel<<<9216, 64, 0, stream>>>(x, Wq, Wk, Wv, Wo, XsN, Wt);

  gemm_bt_kernel<<<dim3(544, 1, 1), 256, 0, stream>>>(
      XsN, XsN, sim, 768, 768, N, 24, AMAP_SIM, BMAP_SIM,
      (long)N * 768, (long)N * 768, (long)N * N, 1);
  topk_adj_kernel<<<BATCH * N, 64, 0, stream>>>(sim, mask);

  prep_raw_kernel<<<BATCH * N, 64, 0, stream>>>(x, XsRaw);
  gemm_bt_kernel<<<dim3(6, 64, 1), 256, 0, stream>>>(
      XsRaw, Wt, qkv, 512, 512, 768, 8, AMAP_2T, BMAP_2T, 0, 0, 0, 0);

  attn_kernel<<<(BATCH * N) / 4, 256, 0, stream>>>(qkv, mask, aos);

  gemm_bt_kernel<<<dim3(2, 64, 1), 256, 0, stream>>>(
      aos, Wt + (size_t)768 * 512, proj, 512, 512, D, 8, AMAP_2T, BMAP_2T, 0, 0, 0, 0);
  ln_kernel<<<BATCH * N, 64, 0, stream>>>(x, proj, bo, gamma, beta, out);
}